// Round 6
// baseline (550.649 us; speedup 1.0000x reference)
//
#include <hip/hip_runtime.h>
#include <float.h>

// VQ: B=32, C=64, H=64, W=64, N_EMBED=512
#define C_DIM   64
#define K_CODES 512
#define HW_BITS 12              // HW = 4096
#define N_TOK   131072
#define TPB     64              // tokens per block
#define NW      8               // waves per block; wave w owns codes [64w, 64w+64)

// Prep: transpose embed [C][K] -> eT [K][C], and norms[k] = ||e_k||^2.
__global__ __launch_bounds__(256) void vq_prep(const float* __restrict__ embed,
                                               float* __restrict__ eT,
                                               float* __restrict__ norms) {
    int k = blockIdx.x * blockDim.x + threadIdx.x;
    if (k >= K_CODES) return;
    float s = 0.f;
    #pragma unroll
    for (int c = 0; c < C_DIM; ++c) {
        float v = embed[c * K_CODES + k];   // coalesced across k
        eT[k * C_DIM + c] = v;
        s = fmaf(v, v, s);
    }
    norms[k] = s;
}

// lane = code (e[64] pinned in VGPRs). f comes in via the SCALAR pipe:
// 4 consecutive tokens' channel c is one wave-uniform 16B load -> s_load,
// consumed as the SGPR operand of v_fma. No LDS staging at all.
__global__ __launch_bounds__(512, 4) void vq_main(const float* __restrict__ x,
                                                  const float* __restrict__ eT,
                                                  const float* __restrict__ norms,
                                                  float* __restrict__ out_qwg,
                                                  float* __restrict__ out_q,
                                                  float* __restrict__ out_ind) {
    __shared__ float sSc[NW][TPB];   // per-wave best score per token
    __shared__ int   sIx[NW][TPB];   // per-wave best code per token
    __shared__ int   gkL[TPB];       // merged winner per token

    const int tid  = threadIdx.x;
    const int lane = tid & 63;
    const int w    = tid >> 6;                 // wave id 0..7
    const int tok0 = blockIdx.x << 6;
    const int b    = tok0 >> HW_BITS;
    const int hw0  = tok0 & ((1 << HW_BITS) - 1);

    // ---- this lane's code row -> VGPRs, pinned so it cannot be rematerialized ----
    const int code = (w << 6) + lane;
    float e[C_DIM];
    {
        const float4* er = (const float4*)(eT + ((size_t)code << 6));
        #pragma unroll
        for (int c4 = 0; c4 < 16; ++c4) {
            float4 v = er[c4];
            e[c4 * 4 + 0] = v.x;
            e[c4 * 4 + 1] = v.y;
            e[c4 * 4 + 2] = v.z;
            e[c4 * 4 + 3] = v.w;
        }
    }
#define PIN16(B)                                                                   \
    asm volatile("" : "+v"(e[B+0]), "+v"(e[B+1]), "+v"(e[B+2]), "+v"(e[B+3]),      \
                      "+v"(e[B+4]), "+v"(e[B+5]), "+v"(e[B+6]), "+v"(e[B+7]),      \
                      "+v"(e[B+8]), "+v"(e[B+9]), "+v"(e[B+10]), "+v"(e[B+11]),    \
                      "+v"(e[B+12]), "+v"(e[B+13]), "+v"(e[B+14]), "+v"(e[B+15]))
    PIN16(0); PIN16(16); PIN16(32); PIN16(48);
#undef PIN16
    const float nrm = norms[code];

    const float* xg = x + ((size_t)b << 18) + hw0;   // wave-uniform base

    // ---- main loop: 16 groups of 4 tokens ----
    #pragma unroll 1
    for (int g = 0; g < 16; ++g) {
        float ac[4][4] = {{0.f,0.f,0.f,0.f},{0.f,0.f,0.f,0.f},
                          {0.f,0.f,0.f,0.f},{0.f,0.f,0.f,0.f}};  // [token][chain]
        #pragma unroll
        for (int c = 0; c < C_DIM; ++c) {            // FULLY unrolled: e[c], c&3 static
            // wave-uniform 16B: tokens (4g..4g+3), channel c -> s_load_dwordx4
            float4 fv = *(const float4*)(xg + ((size_t)c << HW_BITS) + (g << 2));
            ac[0][c & 3] = fmaf(fv.x, e[c], ac[0][c & 3]);   // chains = c mod 4,
            ac[1][c & 3] = fmaf(fv.y, e[c], ac[1][c & 3]);   // ascending c: bit-
            ac[2][c & 3] = fmaf(fv.z, e[c], ac[2][c & 3]);   // identical to r1-r5
            ac[3][c & 3] = fmaf(fv.w, e[c], ac[3][c & 3]);
        }
        #pragma unroll
        for (int ti = 0; ti < 4; ++ti) {
            float dot   = (ac[ti][0] + ac[ti][1]) + (ac[ti][2] + ac[ti][3]);
            float score = fmaf(-2.f, dot, nrm);      // same formula as r1-r5
            // wave-wide min; tie-break = lowest lane = lowest code
            float m = score;
            #pragma unroll
            for (int d = 32; d > 0; d >>= 1)
                m = fminf(m, __shfl_xor(m, d, 64));
            unsigned long long bal = __ballot(score == m);
            int winLane = __ffsll((unsigned long long)bal) - 1;
            if (lane == 0) {
                sSc[w][(g << 2) + ti] = m;
                sIx[w][(g << 2) + ti] = (w << 6) + winLane;
            }
        }
    }
    __syncthreads();

    // ---- merge 8 wave-winners per token (ascending w, strict < = first-min) ----
    if (w == 0) {
        float gb = sSc[0][lane];
        int   gk = sIx[0][lane];
        #pragma unroll
        for (int ww = 1; ww < NW; ++ww) {
            float s = sSc[ww][lane];
            if (s < gb) { gb = s; gk = sIx[ww][lane]; }
        }
        gkL[lane] = gk;
        out_ind[tok0 + lane] = (float)gk;
    }
    __syncthreads();

    // ---- epilogue: wave w writes channels [8w, 8w+8) for token = lane ----
    {
        const int t  = lane;
        const int gk = gkL[t];
        const int c0 = w << 3;
        const float* qr = eT + ((size_t)gk << 6) + c0;     // per-lane gather, L2-hot
        float4 q0 = *(const float4*)(qr);
        float4 q1 = *(const float4*)(qr + 4);

        const float* xr = x + ((size_t)b << 18) + hw0 + t; // coalesced, L2-hot
        float fv[8];
        #pragma unroll
        for (int j = 0; j < 8; ++j) fv[j] = xr[(size_t)(c0 + j) << HW_BITS];

        float* o0 = out_qwg + ((size_t)b << 18) + hw0 + t;
        float* o1 = out_q   + ((size_t)b << 18) + hw0 + t;

        o0[(size_t)(c0 + 0) << HW_BITS] = fv[0] + (q0.x - fv[0]);
        o0[(size_t)(c0 + 1) << HW_BITS] = fv[1] + (q0.y - fv[1]);
        o0[(size_t)(c0 + 2) << HW_BITS] = fv[2] + (q0.z - fv[2]);
        o0[(size_t)(c0 + 3) << HW_BITS] = fv[3] + (q0.w - fv[3]);
        o0[(size_t)(c0 + 4) << HW_BITS] = fv[4] + (q1.x - fv[4]);
        o0[(size_t)(c0 + 5) << HW_BITS] = fv[5] + (q1.y - fv[5]);
        o0[(size_t)(c0 + 6) << HW_BITS] = fv[6] + (q1.z - fv[6]);
        o0[(size_t)(c0 + 7) << HW_BITS] = fv[7] + (q1.w - fv[7]);

        o1[(size_t)(c0 + 0) << HW_BITS] = q0.x;
        o1[(size_t)(c0 + 1) << HW_BITS] = q0.y;
        o1[(size_t)(c0 + 2) << HW_BITS] = q0.z;
        o1[(size_t)(c0 + 3) << HW_BITS] = q0.w;
        o1[(size_t)(c0 + 4) << HW_BITS] = q1.x;
        o1[(size_t)(c0 + 5) << HW_BITS] = q1.y;
        o1[(size_t)(c0 + 6) << HW_BITS] = q1.z;
        o1[(size_t)(c0 + 7) << HW_BITS] = q1.w;
    }
}

extern "C" void kernel_launch(void* const* d_in, const int* in_sizes, int n_in,
                              void* d_out, int out_size, void* d_ws, size_t ws_size,
                              hipStream_t stream) {
    const float* x     = (const float*)d_in[0];
    const float* embed = (const float*)d_in[1];

    float* out     = (float*)d_out;
    float* out_qwg = out;                       // 8388608 f32
    float* out_q   = out + (size_t)8388608;     // 8388608 f32
    float* out_ind = out + (size_t)16777216;    // 131072 f32

    float* eT    = (float*)d_ws;                // 512*64 f32 = 128 KB
    float* norms = eT + K_CODES * C_DIM;        // 512 f32

    vq_prep<<<2, 256, 0, stream>>>(embed, eT, norms);
    vq_main<<<N_TOK / TPB, 512, 0, stream>>>(x, eT, norms, out_qwg, out_q, out_ind);
}

// Round 7
// 160.200 us; speedup vs baseline: 3.4373x; 3.4373x over previous
//
#include <hip/hip_runtime.h>
#include <float.h>

// VQ: B=32, C=64, H=64, W=64, N_EMBED=512
#define C_DIM   64
#define K_CODES 512
#define HW_BITS 12            // HW = 4096
#define N_TOK   131072
#define WAVES   4
#define KPW     (K_CODES / WAVES)   // 128 codes per wave

// Prep: transpose embed [C][K] -> eT [K][C], and norms[k] = ||e_k||^2.
__global__ __launch_bounds__(256) void vq_prep(const float* __restrict__ embed,
                                               float* __restrict__ eT,
                                               float* __restrict__ norms) {
    int k = blockIdx.x * blockDim.x + threadIdx.x;
    if (k >= K_CODES) return;
    float s = 0.f;
    #pragma unroll
    for (int c = 0; c < C_DIM; ++c) {
        float v = embed[c * K_CODES + k];   // coalesced across k
        eT[k * C_DIM + c] = v;
        s = fmaf(v, v, s);
    }
    norms[k] = s;
}

// Round-3 structure (lane=token, wave w scans codes [128w,128w+128) via
// wave-uniform s_load) with the register-demotion fix: launch_bounds(256,2)
// relaxes the VGPR budget to 256, and f lives in 16 NAMED float4 variables —
// no array exists for the allocator to demote to AGPRs/scratch.
__global__ __launch_bounds__(256, 2) void vq_main(const float* __restrict__ x,
                                                  const float* __restrict__ eT,
                                                  const float* __restrict__ norms,
                                                  float* __restrict__ out_qwg,
                                                  float* __restrict__ out_q,
                                                  float* __restrict__ out_ind) {
    const int lane = threadIdx.x & 63;
    const int wvu  = __builtin_amdgcn_readfirstlane((int)(threadIdx.x >> 6)); // uniform
    const int tok  = (blockIdx.x << 6) + lane;
    const int b    = tok >> HW_BITS;
    const int hw   = tok & ((1 << HW_BITS) - 1);

    const float* xb = x + ((size_t)b << 18) + hw;   // b*C*HW + hw, per-lane

    // f in 16 named float4s: f<Q> holds channels 4Q..4Q+3 (loads coalesced).
    float4 f0, f1, f2, f3, f4, f5, f6, f7, f8, f9, f10, f11, f12, f13, f14, f15;
#define LOADF(Q)                                                         \
    f##Q = make_float4(xb[(size_t)(4 * Q + 0) << HW_BITS],               \
                       xb[(size_t)(4 * Q + 1) << HW_BITS],               \
                       xb[(size_t)(4 * Q + 2) << HW_BITS],               \
                       xb[(size_t)(4 * Q + 3) << HW_BITS])
    LOADF(0); LOADF(1); LOADF(2); LOADF(3);
    LOADF(4); LOADF(5); LOADF(6); LOADF(7);
    LOADF(8); LOADF(9); LOADF(10); LOADF(11);
    LOADF(12); LOADF(13); LOADF(14); LOADF(15);
#undef LOADF

    const int    k0    = wvu * KPW;
    const float* eBase = eT + ((size_t)k0 << 6);    // wave-uniform -> s_load path
    const float* nBase = norms + k0;

    float best  = FLT_MAX;
    int   bestk = k0;
    #pragma unroll 2
    for (int kk = 0; kk < KPW; ++kk) {
        const float* e = eBase + (kk << 6);   // uniform -> scalar loads
        float d0 = 0.f, d1 = 0.f, d2 = 0.f, d3 = 0.f;
        // chains = c mod 4, ascending c: bit-identical to rounds 1-3
#define STEP(Q)                                   \
        d0 = fmaf(f##Q.x, e[4 * Q + 0], d0);      \
        d1 = fmaf(f##Q.y, e[4 * Q + 1], d1);      \
        d2 = fmaf(f##Q.z, e[4 * Q + 2], d2);      \
        d3 = fmaf(f##Q.w, e[4 * Q + 3], d3);
        STEP(0)  STEP(1)  STEP(2)  STEP(3)
        STEP(4)  STEP(5)  STEP(6)  STEP(7)
        STEP(8)  STEP(9)  STEP(10) STEP(11)
        STEP(12) STEP(13) STEP(14) STEP(15)
#undef STEP
        float dot   = (d0 + d1) + (d2 + d3);
        float score = fmaf(-2.f, dot, nBase[kk]);   // same formula as r1-r3
        if (score < best) { best = score; bestk = k0 + kk; }  // strict < = first min
    }

    __shared__ float sS[WAVES][64];
    __shared__ int   sI[WAVES][64];
    sS[wvu][lane] = best;
    sI[wvu][lane] = bestk;
    __syncthreads();

    // every thread recomputes the global winner (deterministic, all agree)
    float gb = sS[0][lane];
    int   gk = sI[0][lane];
    #pragma unroll
    for (int w = 1; w < WAVES; ++w) {       // compile-time w, ascending chunks
        float s = sS[w][lane];
        int   i = sI[w][lane];
        if (s < gb) { gb = s; gk = i; }     // strict < = first min
    }

    // epilogue: wave wvu writes channels [16*wvu, 16*wvu+16) for its token.
    // All f accesses are NAMED vars selected by literal macro args.
    const float4* eq4 = (const float4*)(eT + ((size_t)gk << 6)) + (wvu << 2);
    float* o0 = out_qwg + ((size_t)b << 18) + hw;
    float* o1 = out_q   + ((size_t)b << 18) + hw;

#define EPI4(J, Q, CB0)                                                     \
    {                                                                       \
        float4 qv = eq4[J];                                                 \
        float4 ff = f##Q;                                                   \
        o0[(size_t)((CB0) + 4 * J + 0) << HW_BITS] = ff.x + (qv.x - ff.x);  \
        o0[(size_t)((CB0) + 4 * J + 1) << HW_BITS] = ff.y + (qv.y - ff.y);  \
        o0[(size_t)((CB0) + 4 * J + 2) << HW_BITS] = ff.z + (qv.z - ff.z);  \
        o0[(size_t)((CB0) + 4 * J + 3) << HW_BITS] = ff.w + (qv.w - ff.w);  \
        o1[(size_t)((CB0) + 4 * J + 0) << HW_BITS] = qv.x;                  \
        o1[(size_t)((CB0) + 4 * J + 1) << HW_BITS] = qv.y;                  \
        o1[(size_t)((CB0) + 4 * J + 2) << HW_BITS] = qv.z;                  \
        o1[(size_t)((CB0) + 4 * J + 3) << HW_BITS] = qv.w;                  \
    }

    if (wvu == 0) {
        EPI4(0, 0, 0)  EPI4(1, 1, 0)  EPI4(2, 2, 0)  EPI4(3, 3, 0)
        out_ind[tok] = (float)gk;
    } else if (wvu == 1) {
        EPI4(0, 4, 16)  EPI4(1, 5, 16)  EPI4(2, 6, 16)  EPI4(3, 7, 16)
    } else if (wvu == 2) {
        EPI4(0, 8, 32)  EPI4(1, 9, 32)  EPI4(2, 10, 32)  EPI4(3, 11, 32)
    } else {
        EPI4(0, 12, 48)  EPI4(1, 13, 48)  EPI4(2, 14, 48)  EPI4(3, 15, 48)
    }
#undef EPI4
}

extern "C" void kernel_launch(void* const* d_in, const int* in_sizes, int n_in,
                              void* d_out, int out_size, void* d_ws, size_t ws_size,
                              hipStream_t stream) {
    const float* x     = (const float*)d_in[0];
    const float* embed = (const float*)d_in[1];

    float* out     = (float*)d_out;
    float* out_qwg = out;                       // 8388608 f32
    float* out_q   = out + (size_t)8388608;     // 8388608 f32
    float* out_ind = out + (size_t)16777216;    // 131072 f32

    float* eT    = (float*)d_ws;                // 512*64 f32 = 128 KB
    float* norms = eT + K_CODES * C_DIM;        // 512 f32

    vq_prep<<<2, 256, 0, stream>>>(embed, eT, norms);
    vq_main<<<N_TOK / 64, 256, 0, stream>>>(x, eT, norms, out_qwg, out_q, out_ind);
}